// Round 8
// baseline (173.364 us; speedup 1.0000x reference)
//
#include <hip/hip_runtime.h>
#include <hip/hip_bf16.h>
#include <math.h>

// ---------------- workspace layout (float indices) ----------------
// [0,192)     : refsum partials  [bc=48][chunk=4]
// [192,256)   : gates[b*4+e]
// [256,24832) : gate-dot partials [c=3][chunk=64][b=16][8]  (G[4] then N[4]) - deterministic
// [24832,25088): packed conv1 bias f32x4 (64 float4)  [channel-permuted, C-operand form]
// [25088,29184): packed conv1 A-frags  (1024 uint4)  [channel-permuted, see chan()]
// [29184,31232): packed conv2 B-frags  (512 uint4)
#define WS_GATE 192
#define WS_GNP  256
#define WS_B1P  24832
#define WS_W1F  25088
#define WS_W2F  29184

typedef float    float4v __attribute__((ext_vector_type(4)));
typedef short    short8v __attribute__((ext_vector_type(8)));
typedef _Float16 half8v  __attribute__((ext_vector_type(8)));
typedef _Float16 half2v  __attribute__((ext_vector_type(2)));

union Q4 { uint4 q; short8v s; half8v h; };
union H2 { unsigned u; half2v h; };

__device__ __forceinline__ unsigned short bf16b(float f) {
    unsigned u = __builtin_bit_cast(unsigned, f);
    u = (u + 0x7FFFu + ((u >> 16) & 1u)) >> 16;   // RNE
    return (unsigned short)u;
}

__device__ __forceinline__ unsigned pkbf16(float a, float b) {
#if __has_builtin(__builtin_amdgcn_cvt_pk_bf16_f32)
    return __builtin_bit_cast(unsigned, __builtin_amdgcn_cvt_pk_bf16_f32(a, b));
#else
    return (unsigned)bf16b(a) | ((unsigned)bf16b(b) << 16);
#endif
}

__device__ __forceinline__ unsigned pkf16(float a, float b) {
#if __has_builtin(__builtin_amdgcn_cvt_pkrtz)
    return __builtin_bit_cast(unsigned, __builtin_amdgcn_cvt_pkrtz(a, b));
#else
    union { _Float16 h[2]; unsigned u; } p;
    p.h[0] = (_Float16)a; p.h[1] = (_Float16)b;
    return p.u;
#endif
}

__device__ __forceinline__ half2v pkmax0(half2v a) {
#if __has_builtin(__builtin_elementwise_max)
    return __builtin_elementwise_max(a, (half2v){(_Float16)0, (_Float16)0});
#else
    half2v r;
    r[0] = a[0] > (_Float16)0 ? a[0] : (_Float16)0;
    r[1] = a[1] > (_Float16)0 ? a[1] : (_Float16)0;
    return r;
#endif
}

// Same-wave LDS producer->consumer fence.
__device__ __forceinline__ void wave_fence() {
    asm volatile("s_waitcnt lgkmcnt(0)" ::: "memory");
}

// ---------------- kernel AUX: refsum (0..191) | gatedots (192..383) | prep (384) ----------------
__global__ void k_aux(const float* __restrict__ ref, const float* __restrict__ x,
                      const float* __restrict__ wg,  const float* __restrict__ wn,
                      const float* __restrict__ ew1, const float* __restrict__ ew2,
                      const float* __restrict__ eb1,
                      float* __restrict__ ws) {
    __shared__ float sh[4][16][8];
    int blk = blockIdx.x, t = threadIdx.x;

    if (blk < 192) {
        // ---- refsum partials: bc = blk>>2, chunk = blk&3 ----
        int bc = blk >> 2, chunk = blk & 3;
        const float4* p4 = (const float4*)(ref + (size_t)bc*65536 + (size_t)chunk*16384);
        float acc = 0.f;
        #pragma unroll
        for (int i = 0; i < 16; ++i) { float4 v = p4[i*256 + t]; acc += v.x + v.y + v.z + v.w; }
        #pragma unroll
        for (int m = 1; m <= 32; m <<= 1) acc += __shfl_xor(acc, m);
        if ((t & 63) == 0) sh[0][0][t >> 6] = acc;
        __syncthreads();
        if (t == 0) ws[bc*4 + chunk] = sh[0][0][0] + sh[0][0][1] + sh[0][0][2] + sh[0][0][3];
        return;
    }
    if (blk < 384) {
        // ---- gate-dot partials: wg/wn read exactly once; DETERMINISTIC per-chunk slots ----
        int r = blk - 192;
        int c = r >> 6, chunk = r & 63;
        int lane = t & 63, wv = t >> 6;
        int hw0 = chunk*1024 + t*4;
        const float4* wg4 = (const float4*)wg;
        const float4* wn4 = (const float4*)wn;
        const float4* x4  = (const float4*)x;
        float4 G[4], Nw[4];
        #pragma unroll
        for (int i = 0; i < 4; ++i) {
            G[i]  = wg4[c*65536 + hw0 + i];
            Nw[i] = wn4[c*65536 + hw0 + i];
        }
        for (int b = 0; b < 16; ++b) {
            float4 xv = x4[(b*3 + c)*16384 + chunk*256 + t];
            float xs[4] = {xv.x, xv.y, xv.z, xv.w};
            float aG[4] = {0,0,0,0}, aN[4] = {0,0,0,0};
            #pragma unroll
            for (int i = 0; i < 4; ++i) {
                aG[0] += xs[i]*G[i].x;  aG[1] += xs[i]*G[i].y;
                aG[2] += xs[i]*G[i].z;  aG[3] += xs[i]*G[i].w;
                aN[0] += xs[i]*Nw[i].x; aN[1] += xs[i]*Nw[i].y;
                aN[2] += xs[i]*Nw[i].z; aN[3] += xs[i]*Nw[i].w;
            }
            #pragma unroll
            for (int m = 1; m <= 32; m <<= 1) {
                #pragma unroll
                for (int e = 0; e < 4; ++e) {
                    aG[e] += __shfl_xor(aG[e], m);
                    aN[e] += __shfl_xor(aN[e], m);
                }
            }
            if (lane == 0) {
                #pragma unroll
                for (int e = 0; e < 4; ++e) { sh[wv][b][e] = aG[e]; sh[wv][b][4+e] = aN[e]; }
            }
        }
        __syncthreads();
        if (t < 128) {
            int b = t >> 3, s = t & 7;
            float v = sh[0][b][s] + sh[1][b][s] + sh[2][b][s] + sh[3][b][s];
            ws[WS_GNP + ((size_t)(c*64 + chunk)*16 + b)*8 + s] = v;
        }
        return;
    }
    // ---- prep: pack conv weights + bias into MFMA-ready frags ----
    // Channel permutation: conv1 MFMA f, D-row rho produces ORIGINAL channel
    //   chan(f,rho) = (rho>>2)*8 + (f&1)*4 + (rho&3) + (f>>1)*32
    // so that lane (qq,mm) ends holding channels {qq*8..qq*8+7} (f=0,1) and
    // {32+qq*8..+7} (f=2,3) of pixel mm == conv2's A-fragment, in-register.
    uint4* w1f = (uint4*)(ws + WS_W1F);
    for (int i = t; i < 1024; i += 256) {   // i = ((e*4+f)*4+qq)*16+mm ; A-row = mm
        int mm = i & 15, r = i >> 4, qq = r & 3, r2 = r >> 2, f = r2 & 3, e = r2 >> 2;
        int chan = (mm >> 2)*8 + (f & 1)*4 + (mm & 3) + (f >> 1)*32;
        const float* w1 = ew1 + e*1728 + chan*27 + qq*8;
        int navail = 27 - qq*8;             // 8,8,8,3 (k>=27 zero-padded => B-frag garbage OK)
        float v[8];
        #pragma unroll
        for (int j = 0; j < 8; ++j) v[j] = (j < navail) ? w1[j] : 0.f;
        uint4 q;
        q.x = pkbf16(v[0], v[1]); q.y = pkbf16(v[2], v[3]);
        q.z = pkbf16(v[4], v[5]); q.w = pkbf16(v[6], v[7]);
        w1f[i] = q;
    }
    uint4* w2f = (uint4*)(ws + WS_W2F);
    for (int i = t; i < 512; i += 256) {    // i = ((e*16+mm)*2+ks)*4+qq
        int qq = i & 3, r = i >> 2, ks = r & 1, r2 = r >> 1, mm = r2 & 15, e = r2 >> 4;
        uint4 q = make_uint4(0, 0, 0, 0);
        if (mm < 9) {                       // tap = mm, c = ks*32+qq*8+j (original labels)
            float v[8];
            #pragma unroll
            for (int j = 0; j < 8; ++j) v[j] = ew2[e*576 + (ks*32 + qq*8 + j)*9 + mm];
            q.x = pkf16(v[0], v[1]); q.y = pkf16(v[2], v[3]);
            q.z = pkf16(v[4], v[5]); q.w = pkf16(v[6], v[7]);
        }
        w2f[i] = q;
    }
    // packed conv1 bias as f32x4 C-operand: [(e*4+f)*4+qq] holds bias for D-rows qq*4+r
    // = original channels qq*8 + (f&1)*4 + r + (f>>1)*32  (contiguous in r)
    float4* b1pf = (float4*)(ws + WS_B1P);
    if (t < 64) {
        int qq = t & 3, r = t >> 2, f = r & 3, e = r >> 2;
        b1pf[t] = *(const float4*)(eb1 + e*64 + qq*8 + (f & 1)*4 + (f >> 1)*32);
    }
}

// -------- kernel C: reduce partials (fixed order, coalesced) + prompt + top-k + gates + loss ----
__global__ void k_gating(const float* __restrict__ noise,
                         const float* __restrict__ mw1, const float* __restrict__ mb1,
                         const float* __restrict__ mw2, const float* __restrict__ mb2,
                         const float* __restrict__ enw, const float* __restrict__ enb,
                         const float* __restrict__ fp,
                         float* __restrict__ ws, float* __restrict__ out) {
    __shared__ float GN2[48*8];          // [(b*3+c)][4G|4N]
    __shared__ float gL[16][4], pL[16][4], cvs[2];
    int t = threadIdx.x;                 // 128 threads
    {
        // thread t owns (b = t>>3, s = t&7); plane (c,ch) is 128 consecutive floats
        // so each load below is a fully-coalesced 512B wavefront read. Summation
        // order over ch is ascending, identical to the previous serial order.
        int b = t >> 3, s = t & 7;
        #pragma unroll
        for (int c = 0; c < 3; ++c) {
            float v = 0.f;
            #pragma unroll 8
            for (int ch = 0; ch < 64; ++ch)
                v += ws[WS_GNP + (size_t)(c*64 + ch)*128 + t];
            GN2[(b*3 + c)*8 + s] = v;
        }
    }
    __syncthreads();
    if (t < 16) {
        int b = t;
        float sc[3];
        for (int c = 0; c < 3; ++c) {
            int bc = b*3 + c;
            sc[c] = (ws[bc*4] + ws[bc*4+1] + ws[bc*4+2] + ws[bc*4+3]) * (1.f/256.f);
        }
        float pooled[12];
        for (int i = 0; i < 12; ++i) { int r = i % 6; pooled[i] = (r < 3) ? sc[r] : 0.f; }
        float m1[6];
        for (int o = 0; o < 6; ++o) {
            float a = mb1[o];
            for (int i = 0; i < 12; ++i) a += mw1[o*12 + i] * pooled[i];
            m1[o] = fmaxf(a, 0.f);
        }
        float m2[6];
        for (int o = 0; o < 6; ++o) {
            float a = mb2[o];
            for (int i = 0; i < 6; ++i) a += mw2[o*6 + i] * m1[i];
            m2[o] = a * fp[(size_t)o * 33024];   // * fre_prompt[o,0,0]
        }
        float dc[3];
        for (int o = 0; o < 3; ++o) {            // only real-part channels matter
            float a = enb[o];
            for (int i = 0; i < 6; ++i) a += enw[o*6 + i] * m2[i];
            dc[o] = fmaxf(a, 0.f) * (1.f/256.f); // mean of irfft2 = Re(DC)/256
        }
        float mx = fmaxf(dc[0], fmaxf(dc[1], dc[2]));
        float e0 = expf(dc[0]-mx), e1 = expf(dc[1]-mx), e2 = expf(dc[2]-mx);
        float inv = 1.f / (e0 + e1 + e2);
        float pc[3] = { e0*inv + 1.f, e1*inv + 1.f, e2*inv + 1.f };
        float cl[4], sg[4], nz[4];
        for (int e = 0; e < 4; ++e) {
            float a = 0.f, nr = 0.f;
            for (int c = 0; c < 3; ++c) {
                a  += pc[c] * GN2[(b*3 + c)*8 + e];
                nr += pc[c] * GN2[(b*3 + c)*8 + 4 + e];
            }
            cl[e] = a;
            float sp = (nr > 20.f) ? nr : log1pf(expf(nr));
            sg[e] = sp + 0.01f;
            nz[e] = a + noise[b*4 + e] * sg[e];
        }
        int i0 = 0; float v0 = nz[0];
        for (int e = 1; e < 4; ++e) if (nz[e] > v0) { v0 = nz[e]; i0 = e; }
        int i1 = -1; float v1 = -3.4e38f;
        for (int e = 0; e < 4; ++e) if (e != i0 && nz[e] > v1) { v1 = nz[e]; i1 = e; }
        float v2 = -3.4e38f;
        for (int e = 0; e < 4; ++e) if (e != i0 && e != i1 && nz[e] > v2) v2 = nz[e];
        float ex = expf(v1 - v0), den = 1.f + ex;
        float gate[4] = {0.f, 0.f, 0.f, 0.f};
        gate[i0] = 1.f/den; gate[i1] = ex/den;
        for (int e = 0; e < 4; ++e) {
            ws[WS_GATE + b*4 + e] = gate[e];
            gL[b][e] = gate[e];
            float thr = (nz[e] > v2) ? v2 : v1;   // thr_in = 3rd-largest, thr_out = 2nd
            pL[b][e] = 0.5f * (1.f + erff((cl[e] - thr) / sg[e] * 0.70710678118f));
        }
    }
    __syncthreads();
    if (t < 2) {
        float v[4];
        for (int e = 0; e < 4; ++e) {
            float s = 0.f;
            for (int b = 0; b < 16; ++b) s += (t == 0) ? gL[b][e] : pL[b][e];
            v[e] = s;
        }
        float mean = 0.25f * (v[0] + v[1] + v[2] + v[3]);
        float var = 0.f;
        for (int e = 0; e < 4; ++e) { float d = v[e] - mean; var += d*d; }
        var *= (1.f/3.f);
        cvs[t] = var / (mean*mean + 1e-10f);
    }
    __syncthreads();
    if (t == 0) out[1048576] = (cvs[0] + cvs[1]) * 0.01f;
}

// -------- kernel D: fused expert convs, zero-exchange (channel-permuted weights) --------
// Wave wv owns output rows 4*wv..4*wv+3. chan() permutation makes each lane's conv1
// MFMA outputs (packed to f16) BE conv2's A-fragment: no LDS exchange. s_T only in
// LDS; in_s aliases it. Interior tiles load the [3][20][24] window as 360 float4s.
// __launch_bounds__(256,5): VGPR cap 102, measured demand 52 -> 5 blocks/CU, 20 waves.
// History: (256,4)=no spill @52 VGPR; (256,6)=SPILLS (cap 85, R3/R5: WRITE_SIZE 25-47MB).
// Tripwire for this round: WRITE_SIZE must stay ~4.1 MB, else revert to (256,4).
__global__ __launch_bounds__(256, 5)
void k_experts(const float* __restrict__ x, const float* __restrict__ eb2,
               const float* __restrict__ ws, float* __restrict__ out) {
    __shared__ __align__(16) char s_raw[16704];     // union: in_s f32[3][20][24] | s_T f32[4][9][116]
    float* in_s = (float*)s_raw;
    typedef float sT_t[9][116];
    sT_t* s_T = (sT_t*)s_raw;

    int t = threadIdx.x;
    int bid = blockIdx.x;
    int logical = (bid & 7) * 512 + (bid >> 3);      // XCD-affinity stripe
    int b = logical >> 8, tile = logical & 255;
    int ty0 = (tile >> 4) * 16, tx0 = (tile & 15) * 16;
    const float* xb = x + (size_t)b * 196608;

    bool interior = (ty0 > 0) && (ty0 < 240) && (tx0 > 0) && (tx0 < 240);

    // ---- load input tile f32 [3][20][24], window origin (ty0-2, tx0-4) ----
    if (interior) {
        // 360 float4s, 16B-aligned ((tx0-4)*4B ≡ 0 mod 16), all in-bounds.
        float4* in_s4 = (float4*)in_s;
        int base4 = ((ty0 - 2)*256 + tx0 - 4) >> 2;   // float4 index of window origin
        const float4* xb4 = (const float4*)xb;
        #pragma unroll
        for (int it = 0; it < 2; ++it) {
            int idx = t + it*256;
            if (idx < 360) {
                int ci = idx / 120, rem = idx - ci*120;
                int iy = rem / 6,   ix4 = rem - iy*6;
                in_s4[idx] = xb4[ci*16384 + iy*64 + ix4 + base4];
            }
        }
    } else {
        for (int i = t; i < 1440; i += 256) {
            int ci = i / 480, r = i - ci*480, iy = r / 24, ix = r - iy*24;
            int gy = ty0 - 2 + iy, gx = tx0 - 4 + ix;
            float v = 0.f;
            if ((unsigned)gy < 256u && (unsigned)gx < 256u) v = xb[ci*65536 + gy*256 + gx];
            in_s[i] = v;
        }
    }
    __syncthreads();

    int lane = t & 63, wv = t >> 6;
    int qq = lane >> 4, mm = lane & 15;

    // per-lane k->tile-offset map (k = qq*8+j), stride-24 rows; k>=27 -> addr 0 (weights 0)
    int offj[8];
    #pragma unroll
    for (int j = 0; j < 8; ++j) {
        int k = qq*8 + j;
        if (k < 27) { int ci = k/9, r = k - ci*9, kh = r/3, kw = r - kh*3;
                      offj[j] = ci*480 + kh*24 + kw; }
        else offj[j] = 0;
    }

    // ---- build conv1 B-frags: wave wv owns hidden pixels [72*wv + 16*grp, +16) ----
    // Border mask kept as a 7-bit per-lane bitfield (1 VGPR).
    Q4 bfr[7];
    unsigned mskbits = 0;
    #pragma unroll
    for (int grp = 0; grp < 7; ++grp) {
        int p = wv*72 + grp*16 + mm;
        int py = p/18, px = p - py*18;
        int base = (p < 324) ? (py*24 + px + 2) : 0;   // col = 2 + px + kw
        float v[8];
        #pragma unroll
        for (int j = 0; j < 8; ++j)
            v[j] = in_s[base + offj[j]];            // no mask: garbage * 0-weight = 0
        bfr[grp].q.x = pkbf16(v[0], v[1]); bfr[grp].q.y = pkbf16(v[2], v[3]);
        bfr[grp].q.z = pkbf16(v[4], v[5]); bfr[grp].q.w = pkbf16(v[6], v[7]);
        int gy = ty0 - 1 + py, gx = tx0 - 1 + px;
        if (((unsigned)gy < 256u) && ((unsigned)gx < 256u)) mskbits |= (1u << grp);
    }
    __syncthreads();   // all waves done with in_s before any s_T write (aliased)

    const float4 gates = *(const float4*)(ws + WS_GATE + b*4);
    float gv[4] = {gates.x, gates.y, gates.z, gates.w};
    const uint4*  w1f  = (const uint4*)(ws + WS_W1F);
    const uint4*  w2f  = (const uint4*)(ws + WS_W2F);
    const float4* b1pf = (const float4*)(ws + WS_B1P);
    float accY = 0.f;

    for (int e = 0; e < 4; ++e) {
        float gval = gv[e];
        if (gval == 0.f) continue;                 // block-uniform (exactly 2 active)

        // pre-packed conv2 B-frags
        Q4 bw0, bw1;
        bw0.q = w2f[((e*16 + mm)*2 + 0)*4 + qq];
        bw1.q = w2f[((e*16 + mm)*2 + 1)*4 + qq];
        // pre-packed (channel-permuted) conv1 A-frags + f32 bias C-operands
        Q4 af[4]; float4v bc4[4];
        #pragma unroll
        for (int f = 0; f < 4; ++f) {
            af[f].q = w1f[((e*4 + f)*4 + qq)*16 + mm];
            float4 bb = b1pf[(e*4 + f)*4 + qq];
            bc4[f] = (float4v){bb.x, bb.y, bb.z, bb.w};
        }

        #pragma unroll
        for (int grp = 0; grp < 7; ++grp) {
            // border mask as f16x2 {0,0} or {1,1} from the bitfield
            H2 mv;
            if (!interior) mv.u = ((mskbits >> grp) & 1u) ? 0x3C003C00u : 0u;
            // conv1 (+bias in C): lane (qq,mm) -> channels {qq*8+j, 32+qq*8+j} of pixel mm
            Q4 a0, a1;
            #pragma unroll
            for (int f = 0; f < 4; ++f) {
                float4v d = __builtin_amdgcn_mfma_f32_16x16x32_bf16(
                    af[f].s, bfr[grp].s, bc4[f], 0, 0, 0);
                H2 h01, h23;
                h01.u = pkf16(d[0], d[1]);
                h23.u = pkf16(d[2], d[3]);
                h01.h = pkmax0(h01.h);
                h23.h = pkmax0(h23.h);
                if (!interior) { h01.h = h01.h * mv.h; h23.h = h23.h * mv.h; }
                if      (f == 0) { a0.q.x = h01.u; a0.q.y = h23.u; }
                else if (f == 1) { a0.q.z = h01.u; a0.q.w = h23.u; }
                else if (f == 2) { a1.q.x = h01.u; a1.q.y = h23.u; }
                else             { a1.q.z = h01.u; a1.q.w = h23.u; }
            }
            // conv2 stage 1, direct from registers: T[pixel][tap]
            float4v d2 = __builtin_amdgcn_mfma_f32_16x16x32_f16(
                a0.h, bw0.h, (float4v){0.f,0.f,0.f,0.f}, 0, 0, 0);
            d2 = __builtin_amdgcn_mfma_f32_16x16x32_f16(a1.h, bw1.h, d2, 0, 0, 0);
            if (mm < 9)            // tap = mm; rows = wave-local pixels grp*16+qq*4+r
                *(float4*)&s_T[wv][mm][grp*16 + qq*4] = make_float4(d2[0], d2[1], d2[2], d2[3]);
        }
        wave_fence();   // s_T writes complete before same-wave reads

        // stage 2: out = sum_tap T[(qq+kh)*18 + mm+kw][tap]   (all same-wave data)
        float oacc = 0.f;
        #pragma unroll
        for (int kh = 0; kh < 3; ++kh) {
            #pragma unroll
            for (int kw = 0; kw < 3; ++kw)
                oacc += s_T[wv][kh*3 + kw][(qq + kh)*18 + mm + kw];
        }
        wave_fence();       // T reads done before next expert's stage-1 stores
        accY += gval * (oacc + eb2[e]);
    }
    // wave wv, lane (qq,mm) -> output row ty0 + 4*wv + qq, col tx0 + mm
    out[(size_t)b*65536 + (ty0 + wv*4 + qq)*256 + tx0 + mm] = accY;
}

extern "C" void kernel_launch(void* const* d_in, const int* in_sizes, int n_in,
                              void* d_out, int out_size, void* d_ws, size_t ws_size,
                              hipStream_t stream) {
    (void)in_sizes; (void)n_in; (void)out_size; (void)ws_size;
    const float* x     = (const float*)d_in[0];
    const float* ref   = (const float*)d_in[1];
    const float* noise = (const float*)d_in[2];
    const float* mw1   = (const float*)d_in[3];
    const float* mb1   = (const float*)d_in[4];
    const float* mw2   = (const float*)d_in[5];
    const float* mb2   = (const float*)d_in[6];
    const float* enw   = (const float*)d_in[7];
    const float* enb   = (const float*)d_in[8];
    const float* fp    = (const float*)d_in[9];
    const float* wg    = (const float*)d_in[10];
    const float* wn    = (const float*)d_in[11];
    const float* ew1   = (const float*)d_in[12];
    const float* eb1   = (const float*)d_in[13];
    const float* ew2   = (const float*)d_in[14];
    const float* eb2   = (const float*)d_in[15];
    float* out = (float*)d_out;
    float* ws  = (float*)d_ws;

    k_aux    <<<385, 256, 0, stream>>>(ref, x, wg, wn, ew1, ew2, eb1, ws);
    k_gating <<<1, 128, 0, stream>>>(noise, mw1, mb1, mw2, mb2, enw, enb, fp, ws, out);
    k_experts<<<4096, 256, 0, stream>>>(x, eb2, ws, out);
}

// Round 9
// 169.296 us; speedup vs baseline: 1.0240x; 1.0240x over previous
//
#include <hip/hip_runtime.h>
#include <hip/hip_bf16.h>
#include <math.h>

// ---------------- workspace layout (float indices) ----------------
// [0,192)     : refsum partials  [bc=48][chunk=4]
// [192,256)   : gates[b*4+e]
// [256,24832) : gate-dot partials [c=3][chunk=64][b=16][8]  (G[4] then N[4]) - deterministic
// [24832,25088): packed conv1 bias f32x4 (64 float4)  [channel-permuted, C-operand form]
// [25088,29184): packed conv1 A-frags  (1024 uint4)  [channel-permuted, see chan()]
// [29184,31232): packed conv2 B-frags  (512 uint4)
#define WS_GATE 192
#define WS_GNP  256
#define WS_B1P  24832
#define WS_W1F  25088
#define WS_W2F  29184

typedef float    float4v __attribute__((ext_vector_type(4)));
typedef short    short8v __attribute__((ext_vector_type(8)));
typedef _Float16 half8v  __attribute__((ext_vector_type(8)));
typedef _Float16 half2v  __attribute__((ext_vector_type(2)));

union Q4 { uint4 q; short8v s; half8v h; };
union H2 { unsigned u; half2v h; };

__device__ __forceinline__ unsigned short bf16b(float f) {
    unsigned u = __builtin_bit_cast(unsigned, f);
    u = (u + 0x7FFFu + ((u >> 16) & 1u)) >> 16;   // RNE
    return (unsigned short)u;
}

__device__ __forceinline__ unsigned pkbf16(float a, float b) {
#if __has_builtin(__builtin_amdgcn_cvt_pk_bf16_f32)
    return __builtin_bit_cast(unsigned, __builtin_amdgcn_cvt_pk_bf16_f32(a, b));
#else
    return (unsigned)bf16b(a) | ((unsigned)bf16b(b) << 16);
#endif
}

__device__ __forceinline__ unsigned pkf16(float a, float b) {
#if __has_builtin(__builtin_amdgcn_cvt_pkrtz)
    return __builtin_bit_cast(unsigned, __builtin_amdgcn_cvt_pkrtz(a, b));
#else
    union { _Float16 h[2]; unsigned u; } p;
    p.h[0] = (_Float16)a; p.h[1] = (_Float16)b;
    return p.u;
#endif
}

__device__ __forceinline__ half2v pkmax0(half2v a) {
#if __has_builtin(__builtin_elementwise_max)
    return __builtin_elementwise_max(a, (half2v){(_Float16)0, (_Float16)0});
#else
    half2v r;
    r[0] = a[0] > (_Float16)0 ? a[0] : (_Float16)0;
    r[1] = a[1] > (_Float16)0 ? a[1] : (_Float16)0;
    return r;
#endif
}

// ---------------- kernel AUX: refsum (0..191) | gatedots (192..383) | prep (384) ----------------
__global__ void k_aux(const float* __restrict__ ref, const float* __restrict__ x,
                      const float* __restrict__ wg,  const float* __restrict__ wn,
                      const float* __restrict__ ew1, const float* __restrict__ ew2,
                      const float* __restrict__ eb1,
                      float* __restrict__ ws) {
    __shared__ float sh[4][16][8];
    int blk = blockIdx.x, t = threadIdx.x;

    if (blk < 192) {
        // ---- refsum partials: bc = blk>>2, chunk = blk&3 ----
        int bc = blk >> 2, chunk = blk & 3;
        const float4* p4 = (const float4*)(ref + (size_t)bc*65536 + (size_t)chunk*16384);
        float acc = 0.f;
        #pragma unroll
        for (int i = 0; i < 16; ++i) { float4 v = p4[i*256 + t]; acc += v.x + v.y + v.z + v.w; }
        #pragma unroll
        for (int m = 1; m <= 32; m <<= 1) acc += __shfl_xor(acc, m);
        if ((t & 63) == 0) sh[0][0][t >> 6] = acc;
        __syncthreads();
        if (t == 0) ws[bc*4 + chunk] = sh[0][0][0] + sh[0][0][1] + sh[0][0][2] + sh[0][0][3];
        return;
    }
    if (blk < 384) {
        // ---- gate-dot partials: wg/wn read exactly once; DETERMINISTIC per-chunk slots ----
        int r = blk - 192;
        int c = r >> 6, chunk = r & 63;
        int lane = t & 63, wv = t >> 6;
        int hw0 = chunk*1024 + t*4;
        const float4* wg4 = (const float4*)wg;
        const float4* wn4 = (const float4*)wn;
        const float4* x4  = (const float4*)x;
        float4 G[4], Nw[4];
        #pragma unroll
        for (int i = 0; i < 4; ++i) {
            G[i]  = wg4[c*65536 + hw0 + i];
            Nw[i] = wn4[c*65536 + hw0 + i];
        }
        for (int b = 0; b < 16; ++b) {
            float4 xv = x4[(b*3 + c)*16384 + chunk*256 + t];
            float xs[4] = {xv.x, xv.y, xv.z, xv.w};
            float aG[4] = {0,0,0,0}, aN[4] = {0,0,0,0};
            #pragma unroll
            for (int i = 0; i < 4; ++i) {
                aG[0] += xs[i]*G[i].x;  aG[1] += xs[i]*G[i].y;
                aG[2] += xs[i]*G[i].z;  aG[3] += xs[i]*G[i].w;
                aN[0] += xs[i]*Nw[i].x; aN[1] += xs[i]*Nw[i].y;
                aN[2] += xs[i]*Nw[i].z; aN[3] += xs[i]*Nw[i].w;
            }
            #pragma unroll
            for (int m = 1; m <= 32; m <<= 1) {
                #pragma unroll
                for (int e = 0; e < 4; ++e) {
                    aG[e] += __shfl_xor(aG[e], m);
                    aN[e] += __shfl_xor(aN[e], m);
                }
            }
            if (lane == 0) {
                #pragma unroll
                for (int e = 0; e < 4; ++e) { sh[wv][b][e] = aG[e]; sh[wv][b][4+e] = aN[e]; }
            }
        }
        __syncthreads();
        if (t < 128) {
            int b = t >> 3, s = t & 7;
            float v = sh[0][b][s] + sh[1][b][s] + sh[2][b][s] + sh[3][b][s];
            ws[WS_GNP + ((size_t)(c*64 + chunk)*16 + b)*8 + s] = v;
        }
        return;
    }
    // ---- prep: pack conv weights + bias into MFMA-ready frags ----
    // Channel permutation: conv1 MFMA f, D-row rho produces ORIGINAL channel
    //   chan(f,rho) = (rho>>2)*8 + (f&1)*4 + (rho&3) + (f>>1)*32
    // so that lane (qq,mm) ends holding channels {qq*8..qq*8+7} (f=0,1) and
    // {32+qq*8..+7} (f=2,3) of pixel mm == conv2's A-fragment, in-register.
    uint4* w1f = (uint4*)(ws + WS_W1F);
    for (int i = t; i < 1024; i += 256) {   // i = ((e*4+f)*4+qq)*16+mm ; A-row = mm
        int mm = i & 15, r = i >> 4, qq = r & 3, r2 = r >> 2, f = r2 & 3, e = r2 >> 2;
        int chan = (mm >> 2)*8 + (f & 1)*4 + (mm & 3) + (f >> 1)*32;
        const float* w1 = ew1 + e*1728 + chan*27 + qq*8;
        int navail = 27 - qq*8;             // 8,8,8,3 (k>=27 zero-padded => B-frag garbage OK)
        float v[8];
        #pragma unroll
        for (int j = 0; j < 8; ++j) v[j] = (j < navail) ? w1[j] : 0.f;
        uint4 q;
        q.x = pkbf16(v[0], v[1]); q.y = pkbf16(v[2], v[3]);
        q.z = pkbf16(v[4], v[5]); q.w = pkbf16(v[6], v[7]);
        w1f[i] = q;
    }
    uint4* w2f = (uint4*)(ws + WS_W2F);
    for (int i = t; i < 512; i += 256) {    // i = ((e*16+mm)*2+ks)*4+qq
        int qq = i & 3, r = i >> 2, ks = r & 1, r2 = r >> 1, mm = r2 & 15, e = r2 >> 4;
        uint4 q = make_uint4(0, 0, 0, 0);
        if (mm < 9) {                       // tap = mm, c = ks*32+qq*8+j (original labels)
            float v[8];
            #pragma unroll
            for (int j = 0; j < 8; ++j) v[j] = ew2[e*576 + (ks*32 + qq*8 + j)*9 + mm];
            q.x = pkf16(v[0], v[1]); q.y = pkf16(v[2], v[3]);
            q.z = pkf16(v[4], v[5]); q.w = pkf16(v[6], v[7]);
        }
        w2f[i] = q;
    }
    // packed conv1 bias as f32x4 C-operand: [(e*4+f)*4+qq] holds bias for D-rows qq*4+r
    // = original channels qq*8 + (f&1)*4 + r + (f>>1)*32  (contiguous in r)
    float4* b1pf = (float4*)(ws + WS_B1P);
    if (t < 64) {
        int qq = t & 3, r = t >> 2, f = r & 3, e = r >> 2;
        b1pf[t] = *(const float4*)(eb1 + e*64 + qq*8 + (f & 1)*4 + (f >> 1)*32);
    }
}

// -------- kernel C: reduce partials (fixed order, coalesced) + prompt + top-k + gates + loss ----
__global__ void k_gating(const float* __restrict__ noise,
                         const float* __restrict__ mw1, const float* __restrict__ mb1,
                         const float* __restrict__ mw2, const float* __restrict__ mb2,
                         const float* __restrict__ enw, const float* __restrict__ enb,
                         const float* __restrict__ fp,
                         float* __restrict__ ws, float* __restrict__ out) {
    __shared__ float GN2[48*8];          // [(b*3+c)][4G|4N]
    __shared__ float gL[16][4], pL[16][4], cvs[2];
    int t = threadIdx.x;                 // 128 threads
    {
        // thread t owns (b = t>>3, s = t&7); plane (c,ch) is 128 consecutive floats
        // so each load below is a fully-coalesced 512B wavefront read. Summation
        // order over ch is ascending, identical to the previous serial order.
        int b = t >> 3, s = t & 7;
        #pragma unroll
        for (int c = 0; c < 3; ++c) {
            float v = 0.f;
            #pragma unroll 8
            for (int ch = 0; ch < 64; ++ch)
                v += ws[WS_GNP + (size_t)(c*64 + ch)*128 + t];
            GN2[(b*3 + c)*8 + s] = v;
        }
    }
    __syncthreads();
    if (t < 16) {
        int b = t;
        float sc[3];
        for (int c = 0; c < 3; ++c) {
            int bc = b*3 + c;
            sc[c] = (ws[bc*4] + ws[bc*4+1] + ws[bc*4+2] + ws[bc*4+3]) * (1.f/256.f);
        }
        float pooled[12];
        for (int i = 0; i < 12; ++i) { int r = i % 6; pooled[i] = (r < 3) ? sc[r] : 0.f; }
        float m1[6];
        for (int o = 0; o < 6; ++o) {
            float a = mb1[o];
            for (int i = 0; i < 12; ++i) a += mw1[o*12 + i] * pooled[i];
            m1[o] = fmaxf(a, 0.f);
        }
        float m2[6];
        for (int o = 0; o < 6; ++o) {
            float a = mb2[o];
            for (int i = 0; i < 6; ++i) a += mw2[o*6 + i] * m1[i];
            m2[o] = a * fp[(size_t)o * 33024];   // * fre_prompt[o,0,0]
        }
        float dc[3];
        for (int o = 0; o < 3; ++o) {            // only real-part channels matter
            float a = enb[o];
            for (int i = 0; i < 6; ++i) a += enw[o*6 + i] * m2[i];
            dc[o] = fmaxf(a, 0.f) * (1.f/256.f); // mean of irfft2 = Re(DC)/256
        }
        float mx = fmaxf(dc[0], fmaxf(dc[1], dc[2]));
        float e0 = expf(dc[0]-mx), e1 = expf(dc[1]-mx), e2 = expf(dc[2]-mx);
        float inv = 1.f / (e0 + e1 + e2);
        float pc[3] = { e0*inv + 1.f, e1*inv + 1.f, e2*inv + 1.f };
        float cl[4], sg[4], nz[4];
        for (int e = 0; e < 4; ++e) {
            float a = 0.f, nr = 0.f;
            for (int c = 0; c < 3; ++c) {
                a  += pc[c] * GN2[(b*3 + c)*8 + e];
                nr += pc[c] * GN2[(b*3 + c)*8 + 4 + e];
            }
            cl[e] = a;
            float sp = (nr > 20.f) ? nr : log1pf(expf(nr));
            sg[e] = sp + 0.01f;
            nz[e] = a + noise[b*4 + e] * sg[e];
        }
        int i0 = 0; float v0 = nz[0];
        for (int e = 1; e < 4; ++e) if (nz[e] > v0) { v0 = nz[e]; i0 = e; }
        int i1 = -1; float v1 = -3.4e38f;
        for (int e = 0; e < 4; ++e) if (e != i0 && nz[e] > v1) { v1 = nz[e]; i1 = e; }
        float v2 = -3.4e38f;
        for (int e = 0; e < 4; ++e) if (e != i0 && e != i1 && nz[e] > v2) v2 = nz[e];
        float ex = expf(v1 - v0), den = 1.f + ex;
        float gate[4] = {0.f, 0.f, 0.f, 0.f};
        gate[i0] = 1.f/den; gate[i1] = ex/den;
        for (int e = 0; e < 4; ++e) {
            ws[WS_GATE + b*4 + e] = gate[e];
            gL[b][e] = gate[e];
            float thr = (nz[e] > v2) ? v2 : v1;   // thr_in = 3rd-largest, thr_out = 2nd
            pL[b][e] = 0.5f * (1.f + erff((cl[e] - thr) / sg[e] * 0.70710678118f));
        }
    }
    __syncthreads();
    if (t < 2) {
        float v[4];
        for (int e = 0; e < 4; ++e) {
            float s = 0.f;
            for (int b = 0; b < 16; ++b) s += (t == 0) ? gL[b][e] : pL[b][e];
            v[e] = s;
        }
        float mean = 0.25f * (v[0] + v[1] + v[2] + v[3]);
        float var = 0.f;
        for (int e = 0; e < 4; ++e) { float d = v[e] - mean; var += d*d; }
        var *= (1.f/3.f);
        cvs[t] = var / (mean*mean + 1e-10f);
    }
    __syncthreads();
    if (t == 0) out[1048576] = (cvs[0] + cvs[1]) * 0.01f;
}

// -------- kernel D: fused expert convs, zero-exchange (channel-permuted weights) --------
// Wave wv owns output rows 4*wv..4*wv+3. chan() permutation makes each lane's conv1
// MFMA outputs (packed to f16) BE conv2's A-fragment: no LDS exchange. s_T only in
// LDS; in_s aliases it. Interior tiles load the [3][20][24] window as 360 float4s.
// NO explicit lgkmcnt fences around s_T: all s_T producer->consumer pairs are
// SAME-WAVE, and CDNA processes a wave's DS ops in order; the compiler cannot
// reorder the may-aliasing LDS accesses and auto-inserts per-read lgkmcnt waits.
// (The removed asm fences forced full DS drains 4x/block and pinned the scheduler.)
// __launch_bounds__(256,4): VGPR cap 128, ~52 used, no spill.
// (256,5) and (256,6) both SPILL (R8: +9MB write, R3/R5: +25-47MB) — do not raise.
__global__ __launch_bounds__(256, 4)
void k_experts(const float* __restrict__ x, const float* __restrict__ eb2,
               const float* __restrict__ ws, float* __restrict__ out) {
    __shared__ __align__(16) char s_raw[16704];     // union: in_s f32[3][20][24] | s_T f32[4][9][116]
    float* in_s = (float*)s_raw;
    typedef float sT_t[9][116];
    sT_t* s_T = (sT_t*)s_raw;

    int t = threadIdx.x;
    int bid = blockIdx.x;
    int logical = (bid & 7) * 512 + (bid >> 3);      // XCD-affinity stripe
    int b = logical >> 8, tile = logical & 255;
    int ty0 = (tile >> 4) * 16, tx0 = (tile & 15) * 16;
    const float* xb = x + (size_t)b * 196608;

    bool interior = (ty0 > 0) && (ty0 < 240) && (tx0 > 0) && (tx0 < 240);

    // ---- load input tile f32 [3][20][24], window origin (ty0-2, tx0-4) ----
    if (interior) {
        // 360 float4s, 16B-aligned ((tx0-4)*4B ≡ 0 mod 16), all in-bounds.
        float4* in_s4 = (float4*)in_s;
        int base4 = ((ty0 - 2)*256 + tx0 - 4) >> 2;   // float4 index of window origin
        const float4* xb4 = (const float4*)xb;
        #pragma unroll
        for (int it = 0; it < 2; ++it) {
            int idx = t + it*256;
            if (idx < 360) {
                int ci = idx / 120, rem = idx - ci*120;
                int iy = rem / 6,   ix4 = rem - iy*6;
                in_s4[idx] = xb4[ci*16384 + iy*64 + ix4 + base4];
            }
        }
    } else {
        for (int i = t; i < 1440; i += 256) {
            int ci = i / 480, r = i - ci*480, iy = r / 24, ix = r - iy*24;
            int gy = ty0 - 2 + iy, gx = tx0 - 4 + ix;
            float v = 0.f;
            if ((unsigned)gy < 256u && (unsigned)gx < 256u) v = xb[ci*65536 + gy*256 + gx];
            in_s[i] = v;
        }
    }
    __syncthreads();

    int lane = t & 63, wv = t >> 6;
    int qq = lane >> 4, mm = lane & 15;

    // per-lane k->tile-offset map (k = qq*8+j), stride-24 rows; k>=27 -> addr 0 (weights 0)
    int offj[8];
    #pragma unroll
    for (int j = 0; j < 8; ++j) {
        int k = qq*8 + j;
        if (k < 27) { int ci = k/9, r = k - ci*9, kh = r/3, kw = r - kh*3;
                      offj[j] = ci*480 + kh*24 + kw; }
        else offj[j] = 0;
    }

    // ---- build conv1 B-frags: wave wv owns hidden pixels [72*wv + 16*grp, +16) ----
    // Border mask kept as a 7-bit per-lane bitfield (1 VGPR).
    Q4 bfr[7];
    unsigned mskbits = 0;
    #pragma unroll
    for (int grp = 0; grp < 7; ++grp) {
        int p = wv*72 + grp*16 + mm;
        int py = p/18, px = p - py*18;
        int base = (p < 324) ? (py*24 + px + 2) : 0;   // col = 2 + px + kw
        float v[8];
        #pragma unroll
        for (int j = 0; j < 8; ++j)
            v[j] = in_s[base + offj[j]];            // no mask: garbage * 0-weight = 0
        bfr[grp].q.x = pkbf16(v[0], v[1]); bfr[grp].q.y = pkbf16(v[2], v[3]);
        bfr[grp].q.z = pkbf16(v[4], v[5]); bfr[grp].q.w = pkbf16(v[6], v[7]);
        int gy = ty0 - 1 + py, gx = tx0 - 1 + px;
        if (((unsigned)gy < 256u) && ((unsigned)gx < 256u)) mskbits |= (1u << grp);
    }
    __syncthreads();   // all waves done with in_s before any s_T write (aliased)

    const float4 gates = *(const float4*)(ws + WS_GATE + b*4);
    float gv[4] = {gates.x, gates.y, gates.z, gates.w};
    const uint4*  w1f  = (const uint4*)(ws + WS_W1F);
    const uint4*  w2f  = (const uint4*)(ws + WS_W2F);
    const float4* b1pf = (const float4*)(ws + WS_B1P);
    float accY = 0.f;

    for (int e = 0; e < 4; ++e) {
        float gval = gv[e];
        if (gval == 0.f) continue;                 // block-uniform (exactly 2 active)

        // pre-packed conv2 B-frags
        Q4 bw0, bw1;
        bw0.q = w2f[((e*16 + mm)*2 + 0)*4 + qq];
        bw1.q = w2f[((e*16 + mm)*2 + 1)*4 + qq];
        // pre-packed (channel-permuted) conv1 A-frags + f32 bias C-operands
        Q4 af[4]; float4v bc4[4];
        #pragma unroll
        for (int f = 0; f < 4; ++f) {
            af[f].q = w1f[((e*4 + f)*4 + qq)*16 + mm];
            float4 bb = b1pf[(e*4 + f)*4 + qq];
            bc4[f] = (float4v){bb.x, bb.y, bb.z, bb.w};
        }

        #pragma unroll
        for (int grp = 0; grp < 7; ++grp) {
            // border mask as f16x2 {0,0} or {1,1} from the bitfield
            H2 mv;
            if (!interior) mv.u = ((mskbits >> grp) & 1u) ? 0x3C003C00u : 0u;
            // conv1 (+bias in C): lane (qq,mm) -> channels {qq*8+j, 32+qq*8+j} of pixel mm
            Q4 a0, a1;
            #pragma unroll
            for (int f = 0; f < 4; ++f) {
                float4v d = __builtin_amdgcn_mfma_f32_16x16x32_bf16(
                    af[f].s, bfr[grp].s, bc4[f], 0, 0, 0);
                H2 h01, h23;
                h01.u = pkf16(d[0], d[1]);
                h23.u = pkf16(d[2], d[3]);
                h01.h = pkmax0(h01.h);
                h23.h = pkmax0(h23.h);
                if (!interior) { h01.h = h01.h * mv.h; h23.h = h23.h * mv.h; }
                if      (f == 0) { a0.q.x = h01.u; a0.q.y = h23.u; }
                else if (f == 1) { a0.q.z = h01.u; a0.q.w = h23.u; }
                else if (f == 2) { a1.q.x = h01.u; a1.q.y = h23.u; }
                else             { a1.q.z = h01.u; a1.q.w = h23.u; }
            }
            // conv2 stage 1, direct from registers: T[pixel][tap]
            float4v d2 = __builtin_amdgcn_mfma_f32_16x16x32_f16(
                a0.h, bw0.h, (float4v){0.f,0.f,0.f,0.f}, 0, 0, 0);
            d2 = __builtin_amdgcn_mfma_f32_16x16x32_f16(a1.h, bw1.h, d2, 0, 0, 0);
            if (mm < 9)            // tap = mm; rows = wave-local pixels grp*16+qq*4+r
                *(float4*)&s_T[wv][mm][grp*16 + qq*4] = make_float4(d2[0], d2[1], d2[2], d2[3]);
        }
        // same-wave in-order DS: stage-2 reads below see the stage-1 writes above
        // without an explicit drain; compiler inserts the per-read lgkmcnt waits.

        // stage 2: out = sum_tap T[(qq+kh)*18 + mm+kw][tap]   (all same-wave data)
        float oacc = 0.f;
        #pragma unroll
        for (int kh = 0; kh < 3; ++kh) {
            #pragma unroll
            for (int kw = 0; kw < 3; ++kw)
                oacc += s_T[wv][kh*3 + kw][(qq + kh)*18 + mm + kw];
        }
        // next expert's s_T writes are same-wave after these reads (in-order DS):
        // write-after-read hazard is ordered by HW; no drain needed.
        accY += gval * (oacc + eb2[e]);
    }
    // wave wv, lane (qq,mm) -> output row ty0 + 4*wv + qq, col tx0 + mm
    out[(size_t)b*65536 + (ty0 + wv*4 + qq)*256 + tx0 + mm] = accY;
}

extern "C" void kernel_launch(void* const* d_in, const int* in_sizes, int n_in,
                              void* d_out, int out_size, void* d_ws, size_t ws_size,
                              hipStream_t stream) {
    (void)in_sizes; (void)n_in; (void)out_size; (void)ws_size;
    const float* x     = (const float*)d_in[0];
    const float* ref   = (const float*)d_in[1];
    const float* noise = (const float*)d_in[2];
    const float* mw1   = (const float*)d_in[3];
    const float* mb1   = (const float*)d_in[4];
    const float* mw2   = (const float*)d_in[5];
    const float* mb2   = (const float*)d_in[6];
    const float* enw   = (const float*)d_in[7];
    const float* enb   = (const float*)d_in[8];
    const float* fp    = (const float*)d_in[9];
    const float* wg    = (const float*)d_in[10];
    const float* wn    = (const float*)d_in[11];
    const float* ew1   = (const float*)d_in[12];
    const float* eb1   = (const float*)d_in[13];
    const float* ew2   = (const float*)d_in[14];
    const float* eb2   = (const float*)d_in[15];
    float* out = (float*)d_out;
    float* ws  = (float*)d_ws;

    k_aux    <<<385, 256, 0, stream>>>(ref, x, wg, wn, ew1, ew2, eb1, ws);
    k_gating <<<1, 128, 0, stream>>>(noise, mw1, mb1, mw2, mb2, enw, enb, fp, ws, out);
    k_experts<<<4096, 256, 0, stream>>>(x, eb2, ws, out);
}

// Round 10
// 168.960 us; speedup vs baseline: 1.0261x; 1.0020x over previous
//
#include <hip/hip_runtime.h>
#include <hip/hip_bf16.h>
#include <math.h>

// ---------------- workspace layout (float indices) ----------------
// [0,192)     : refsum partials  [bc=48][chunk=4]
// [192,256)   : gates[b*4+e]
// [256,24832) : gate-dot partials [c=3][chunk=64][b=16][8]  (G[4] then N[4]) - deterministic
// [24832,25088): packed conv1 bias f32x4 (64 float4)  [channel-permuted, C-operand form]
// [25088,29184): packed conv1 A-frags  (1024 uint4)  [channel-permuted, see chan()]
// [29184,31232): packed conv2 B-frags  (512 uint4)
#define WS_GATE 192
#define WS_GNP  256
#define WS_B1P  24832
#define WS_W1F  25088
#define WS_W2F  29184

typedef float    float4v __attribute__((ext_vector_type(4)));
typedef short    short8v __attribute__((ext_vector_type(8)));
typedef _Float16 half8v  __attribute__((ext_vector_type(8)));
typedef _Float16 half2v  __attribute__((ext_vector_type(2)));

union Q4 { uint4 q; short8v s; half8v h; };
union H2 { unsigned u; half2v h; };

__device__ __forceinline__ unsigned short bf16b(float f) {
    unsigned u = __builtin_bit_cast(unsigned, f);
    u = (u + 0x7FFFu + ((u >> 16) & 1u)) >> 16;   // RNE
    return (unsigned short)u;
}

__device__ __forceinline__ unsigned pkbf16(float a, float b) {
#if __has_builtin(__builtin_amdgcn_cvt_pk_bf16_f32)
    return __builtin_bit_cast(unsigned, __builtin_amdgcn_cvt_pk_bf16_f32(a, b));
#else
    return (unsigned)bf16b(a) | ((unsigned)bf16b(b) << 16);
#endif
}

__device__ __forceinline__ unsigned pkf16(float a, float b) {
#if __has_builtin(__builtin_amdgcn_cvt_pkrtz)
    return __builtin_bit_cast(unsigned, __builtin_amdgcn_cvt_pkrtz(a, b));
#else
    union { _Float16 h[2]; unsigned u; } p;
    p.h[0] = (_Float16)a; p.h[1] = (_Float16)b;
    return p.u;
#endif
}

__device__ __forceinline__ half2v pkmax0(half2v a) {
#if __has_builtin(__builtin_elementwise_max)
    return __builtin_elementwise_max(a, (half2v){(_Float16)0, (_Float16)0});
#else
    half2v r;
    r[0] = a[0] > (_Float16)0 ? a[0] : (_Float16)0;
    r[1] = a[1] > (_Float16)0 ? a[1] : (_Float16)0;
    return r;
#endif
}

// ---------------- kernel AUX: refsum (0..191) | gatedots (192..383) | prep (384) ----------------
__global__ void k_aux(const float* __restrict__ ref, const float* __restrict__ x,
                      const float* __restrict__ wg,  const float* __restrict__ wn,
                      const float* __restrict__ ew1, const float* __restrict__ ew2,
                      const float* __restrict__ eb1,
                      float* __restrict__ ws) {
    __shared__ float sh[4][16][8];
    int blk = blockIdx.x, t = threadIdx.x;

    if (blk < 192) {
        // ---- refsum partials: bc = blk>>2, chunk = blk&3 ----
        int bc = blk >> 2, chunk = blk & 3;
        const float4* p4 = (const float4*)(ref + (size_t)bc*65536 + (size_t)chunk*16384);
        float acc = 0.f;
        #pragma unroll
        for (int i = 0; i < 16; ++i) { float4 v = p4[i*256 + t]; acc += v.x + v.y + v.z + v.w; }
        #pragma unroll
        for (int m = 1; m <= 32; m <<= 1) acc += __shfl_xor(acc, m);
        if ((t & 63) == 0) sh[0][0][t >> 6] = acc;
        __syncthreads();
        if (t == 0) ws[bc*4 + chunk] = sh[0][0][0] + sh[0][0][1] + sh[0][0][2] + sh[0][0][3];
        return;
    }
    if (blk < 384) {
        // ---- gate-dot partials: wg/wn read exactly once; DETERMINISTIC per-chunk slots ----
        int r = blk - 192;
        int c = r >> 6, chunk = r & 63;
        int lane = t & 63, wv = t >> 6;
        int hw0 = chunk*1024 + t*4;
        const float4* wg4 = (const float4*)wg;
        const float4* wn4 = (const float4*)wn;
        const float4* x4  = (const float4*)x;
        float4 G[4], Nw[4];
        #pragma unroll
        for (int i = 0; i < 4; ++i) {
            G[i]  = wg4[c*65536 + hw0 + i];
            Nw[i] = wn4[c*65536 + hw0 + i];
        }
        for (int b = 0; b < 16; ++b) {
            float4 xv = x4[(b*3 + c)*16384 + chunk*256 + t];
            float xs[4] = {xv.x, xv.y, xv.z, xv.w};
            float aG[4] = {0,0,0,0}, aN[4] = {0,0,0,0};
            #pragma unroll
            for (int i = 0; i < 4; ++i) {
                aG[0] += xs[i]*G[i].x;  aG[1] += xs[i]*G[i].y;
                aG[2] += xs[i]*G[i].z;  aG[3] += xs[i]*G[i].w;
                aN[0] += xs[i]*Nw[i].x; aN[1] += xs[i]*Nw[i].y;
                aN[2] += xs[i]*Nw[i].z; aN[3] += xs[i]*Nw[i].w;
            }
            #pragma unroll
            for (int m = 1; m <= 32; m <<= 1) {
                #pragma unroll
                for (int e = 0; e < 4; ++e) {
                    aG[e] += __shfl_xor(aG[e], m);
                    aN[e] += __shfl_xor(aN[e], m);
                }
            }
            if (lane == 0) {
                #pragma unroll
                for (int e = 0; e < 4; ++e) { sh[wv][b][e] = aG[e]; sh[wv][b][4+e] = aN[e]; }
            }
        }
        __syncthreads();
        if (t < 128) {
            int b = t >> 3, s = t & 7;
            float v = sh[0][b][s] + sh[1][b][s] + sh[2][b][s] + sh[3][b][s];
            ws[WS_GNP + ((size_t)(c*64 + chunk)*16 + b)*8 + s] = v;
        }
        return;
    }
    // ---- prep: pack conv weights + bias into MFMA-ready frags ----
    // Channel permutation: conv1 MFMA f, D-row rho produces ORIGINAL channel
    //   chan(f,rho) = (rho>>2)*8 + (f&1)*4 + (rho&3) + (f>>1)*32
    // so that lane (qq,mm) ends holding channels {qq*8..qq*8+7} (f=0,1) and
    // {32+qq*8..+7} (f=2,3) of pixel mm == conv2's A-fragment, in-register.
    uint4* w1f = (uint4*)(ws + WS_W1F);
    for (int i = t; i < 1024; i += 256) {   // i = ((e*4+f)*4+qq)*16+mm ; A-row = mm
        int mm = i & 15, r = i >> 4, qq = r & 3, r2 = r >> 2, f = r2 & 3, e = r2 >> 2;
        int chan = (mm >> 2)*8 + (f & 1)*4 + (mm & 3) + (f >> 1)*32;
        const float* w1 = ew1 + e*1728 + chan*27 + qq*8;
        int navail = 27 - qq*8;             // 8,8,8,3 (k>=27 zero-padded => B-frag garbage OK)
        float v[8];
        #pragma unroll
        for (int j = 0; j < 8; ++j) v[j] = (j < navail) ? w1[j] : 0.f;
        uint4 q;
        q.x = pkbf16(v[0], v[1]); q.y = pkbf16(v[2], v[3]);
        q.z = pkbf16(v[4], v[5]); q.w = pkbf16(v[6], v[7]);
        w1f[i] = q;
    }
    uint4* w2f = (uint4*)(ws + WS_W2F);
    for (int i = t; i < 512; i += 256) {    // i = ((e*16+mm)*2+ks)*4+qq
        int qq = i & 3, r = i >> 2, ks = r & 1, r2 = r >> 1, mm = r2 & 15, e = r2 >> 4;
        uint4 q = make_uint4(0, 0, 0, 0);
        if (mm < 9) {                       // tap = mm, c = ks*32+qq*8+j (original labels)
            float v[8];
            #pragma unroll
            for (int j = 0; j < 8; ++j) v[j] = ew2[e*576 + (ks*32 + qq*8 + j)*9 + mm];
            q.x = pkf16(v[0], v[1]); q.y = pkf16(v[2], v[3]);
            q.z = pkf16(v[4], v[5]); q.w = pkf16(v[6], v[7]);
        }
        w2f[i] = q;
    }
    // packed conv1 bias as f32x4 C-operand: [(e*4+f)*4+qq] holds bias for D-rows qq*4+r
    // = original channels qq*8 + (f&1)*4 + r + (f>>1)*32  (contiguous in r)
    float4* b1pf = (float4*)(ws + WS_B1P);
    if (t < 64) {
        int qq = t & 3, r = t >> 2, f = r & 3, e = r >> 2;
        b1pf[t] = *(const float4*)(eb1 + e*64 + qq*8 + (f & 1)*4 + (f >> 1)*32);
    }
}

// -------- kernel C: reduce partials (fixed order, coalesced) + prompt + top-k + gates + loss ----
__global__ void k_gating(const float* __restrict__ noise,
                         const float* __restrict__ mw1, const float* __restrict__ mb1,
                         const float* __restrict__ mw2, const float* __restrict__ mb2,
                         const float* __restrict__ enw, const float* __restrict__ enb,
                         const float* __restrict__ fp,
                         float* __restrict__ ws, float* __restrict__ out) {
    __shared__ float GN2[48*8];          // [(b*3+c)][4G|4N]
    __shared__ float gL[16][4], pL[16][4], cvs[2];
    int t = threadIdx.x;                 // 128 threads
    {
        // thread t owns (b = t>>3, s = t&7); plane (c,ch) is 128 consecutive floats
        // so each load below is a fully-coalesced 512B wavefront read. Summation
        // order over ch is ascending, identical to the previous serial order.
        int b = t >> 3, s = t & 7;
        #pragma unroll
        for (int c = 0; c < 3; ++c) {
            float v = 0.f;
            #pragma unroll 8
            for (int ch = 0; ch < 64; ++ch)
                v += ws[WS_GNP + (size_t)(c*64 + ch)*128 + t];
            GN2[(b*3 + c)*8 + s] = v;
        }
    }
    __syncthreads();
    if (t < 16) {
        int b = t;
        float sc[3];
        for (int c = 0; c < 3; ++c) {
            int bc = b*3 + c;
            sc[c] = (ws[bc*4] + ws[bc*4+1] + ws[bc*4+2] + ws[bc*4+3]) * (1.f/256.f);
        }
        float pooled[12];
        for (int i = 0; i < 12; ++i) { int r = i % 6; pooled[i] = (r < 3) ? sc[r] : 0.f; }
        float m1[6];
        for (int o = 0; o < 6; ++o) {
            float a = mb1[o];
            for (int i = 0; i < 12; ++i) a += mw1[o*12 + i] * pooled[i];
            m1[o] = fmaxf(a, 0.f);
        }
        float m2[6];
        for (int o = 0; o < 6; ++o) {
            float a = mb2[o];
            for (int i = 0; i < 6; ++i) a += mw2[o*6 + i] * m1[i];
            m2[o] = a * fp[(size_t)o * 33024];   // * fre_prompt[o,0,0]
        }
        float dc[3];
        for (int o = 0; o < 3; ++o) {            // only real-part channels matter
            float a = enb[o];
            for (int i = 0; i < 6; ++i) a += enw[o*6 + i] * m2[i];
            dc[o] = fmaxf(a, 0.f) * (1.f/256.f); // mean of irfft2 = Re(DC)/256
        }
        float mx = fmaxf(dc[0], fmaxf(dc[1], dc[2]));
        float e0 = expf(dc[0]-mx), e1 = expf(dc[1]-mx), e2 = expf(dc[2]-mx);
        float inv = 1.f / (e0 + e1 + e2);
        float pc[3] = { e0*inv + 1.f, e1*inv + 1.f, e2*inv + 1.f };
        float cl[4], sg[4], nz[4];
        for (int e = 0; e < 4; ++e) {
            float a = 0.f, nr = 0.f;
            for (int c = 0; c < 3; ++c) {
                a  += pc[c] * GN2[(b*3 + c)*8 + e];
                nr += pc[c] * GN2[(b*3 + c)*8 + 4 + e];
            }
            cl[e] = a;
            float sp = (nr > 20.f) ? nr : log1pf(expf(nr));
            sg[e] = sp + 0.01f;
            nz[e] = a + noise[b*4 + e] * sg[e];
        }
        int i0 = 0; float v0 = nz[0];
        for (int e = 1; e < 4; ++e) if (nz[e] > v0) { v0 = nz[e]; i0 = e; }
        int i1 = -1; float v1 = -3.4e38f;
        for (int e = 0; e < 4; ++e) if (e != i0 && nz[e] > v1) { v1 = nz[e]; i1 = e; }
        float v2 = -3.4e38f;
        for (int e = 0; e < 4; ++e) if (e != i0 && e != i1 && nz[e] > v2) v2 = nz[e];
        float ex = expf(v1 - v0), den = 1.f + ex;
        float gate[4] = {0.f, 0.f, 0.f, 0.f};
        gate[i0] = 1.f/den; gate[i1] = ex/den;
        for (int e = 0; e < 4; ++e) {
            ws[WS_GATE + b*4 + e] = gate[e];
            gL[b][e] = gate[e];
            float thr = (nz[e] > v2) ? v2 : v1;   // thr_in = 3rd-largest, thr_out = 2nd
            pL[b][e] = 0.5f * (1.f + erff((cl[e] - thr) / sg[e] * 0.70710678118f));
        }
    }
    __syncthreads();
    if (t < 2) {
        float v[4];
        for (int e = 0; e < 4; ++e) {
            float s = 0.f;
            for (int b = 0; b < 16; ++b) s += (t == 0) ? gL[b][e] : pL[b][e];
            v[e] = s;
        }
        float mean = 0.25f * (v[0] + v[1] + v[2] + v[3]);
        float var = 0.f;
        for (int e = 0; e < 4; ++e) { float d = v[e] - mean; var += d*d; }
        var *= (1.f/3.f);
        cvs[t] = var / (mean*mean + 1e-10f);
    }
    __syncthreads();
    if (t == 0) out[1048576] = (cvs[0] + cvs[1]) * 0.01f;
}

// -------- kernel D: fused expert convs, zero-exchange, 16x32 TALL TILES --------
// 2048 blocks; tile = 16 wide x 32 high; wave wv owns output rows 8*wv..8*wv+7.
// Halo amortization: 12 grps / 128 outputs = 1.125 MFMA-groups per output
// (was 7/64 = 1.31) => -14% MFMA + conversions + gather; input window
// [3][36][24] = 5.06 floats/output (was 5.6). Per-output arithmetic is
// BIT-IDENTICAL to the 16x16 version (same MFMA shapes/weights/tap order).
// No explicit DS fences: all s_T producer->consumer pairs are same-wave
// (in-order DS pipe + compiler per-read lgkmcnt).
// __launch_bounds__(256,4): VGPR cap 128; demand ~105 (bfr[12]=48 held).
// Spill tripwire: WRITE_SIZE must stay ~4.1 MB.
__global__ __launch_bounds__(256, 4)
void k_experts(const float* __restrict__ x, const float* __restrict__ eb2,
               const float* __restrict__ ws, float* __restrict__ out) {
    __shared__ __align__(16) char s_raw[28224];  // union: in_s f32[3][36][24] | s_T f32[4][9][196]
    float* in_s = (float*)s_raw;
    typedef float sT_t[9][196];
    sT_t* s_T = (sT_t*)s_raw;

    int t = threadIdx.x;
    int bid = blockIdx.x;
    int logical = (bid & 7) * 256 + (bid >> 3);   // XCD-affinity stripe over 2048
    int b = logical >> 7, tile = logical & 127;   // 8 tile-rows x 16 tile-cols
    int ty0 = (tile >> 4) * 32, tx0 = (tile & 15) * 16;
    const float* xb = x + (size_t)b * 196608;

    // window rows [ty0-2, ty0+33], cols [tx0-4, tx0+19]
    bool interior = (ty0 > 0) && (ty0 < 224) && (tx0 > 0) && (tx0 < 240);

    // ---- load input tile f32 [3][36][24], window origin (ty0-2, tx0-4) ----
    if (interior) {
        // 648 float4s, 16B-aligned, all in-bounds.
        float4* in_s4 = (float4*)in_s;
        int base4 = ((ty0 - 2)*256 + tx0 - 4) >> 2;
        const float4* xb4 = (const float4*)xb;
        #pragma unroll
        for (int it = 0; it < 3; ++it) {
            int idx = t + it*256;
            if (idx < 648) {
                int ci = idx / 216, rem = idx - ci*216;
                int iy = rem / 6,   ix4 = rem - iy*6;
                in_s4[idx] = xb4[ci*16384 + iy*64 + ix4 + base4];
            }
        }
    } else {
        for (int i = t; i < 2592; i += 256) {
            int ci = i / 864, r = i - ci*864, iy = r / 24, ix = r - iy*24;
            int gy = ty0 - 2 + iy, gx = tx0 - 4 + ix;
            float v = 0.f;
            if ((unsigned)gy < 256u && (unsigned)gx < 256u) v = xb[ci*65536 + gy*256 + gx];
            in_s[i] = v;
        }
    }
    __syncthreads();

    int lane = t & 63, wv = t >> 6;
    int qq = lane >> 4, mm = lane & 15;

    // per-lane k->tile-offset map (k = qq*8+j), [3][36][24] layout; k>=27 -> addr 0 (weights 0)
    int offj[8];
    #pragma unroll
    for (int j = 0; j < 8; ++j) {
        int k = qq*8 + j;
        if (k < 27) { int ci = k/9, r = k - ci*9, kh = r/3, kw = r - kh*3;
                      offj[j] = ci*864 + kh*24 + kw; }
        else offj[j] = 0;
    }

    // ---- build conv1 B-frags: wave wv hidden field = 10 rows x 18 cols (180 px, 12 grps) ----
    // hidden local p: py = p/18 (0..9), px = p%18; window input row = 8*wv + py.
    Q4 bfr[12];
    unsigned mskbits = 0;
    #pragma unroll
    for (int grp = 0; grp < 12; ++grp) {
        int p = grp*16 + mm;
        int py = p/18, px = p - py*18;
        int base = (p < 180) ? ((8*wv + py)*24 + px + 2) : 0;
        float v[8];
        #pragma unroll
        for (int j = 0; j < 8; ++j)
            v[j] = in_s[base + offj[j]];            // no mask: garbage * 0-weight = 0
        bfr[grp].q.x = pkbf16(v[0], v[1]); bfr[grp].q.y = pkbf16(v[2], v[3]);
        bfr[grp].q.z = pkbf16(v[4], v[5]); bfr[grp].q.w = pkbf16(v[6], v[7]);
        int gy = ty0 + 8*wv + py - 1, gx = tx0 - 1 + px;
        if (((unsigned)gy < 256u) && ((unsigned)gx < 256u)) mskbits |= (1u << grp);
    }
    __syncthreads();   // all waves done with in_s before any s_T write (aliased)

    const float4 gates = *(const float4*)(ws + WS_GATE + b*4);
    float gv[4] = {gates.x, gates.y, gates.z, gates.w};
    const uint4*  w1f  = (const uint4*)(ws + WS_W1F);
    const uint4*  w2f  = (const uint4*)(ws + WS_W2F);
    const float4* b1pf = (const float4*)(ws + WS_B1P);
    float acc0 = 0.f, acc1 = 0.f;

    for (int e = 0; e < 4; ++e) {
        float gval = gv[e];
        if (gval == 0.f) continue;                 // block-uniform (exactly 2 active)

        // pre-packed conv2 B-frags
        Q4 bw0, bw1;
        bw0.q = w2f[((e*16 + mm)*2 + 0)*4 + qq];
        bw1.q = w2f[((e*16 + mm)*2 + 1)*4 + qq];
        // pre-packed (channel-permuted) conv1 A-frags + f32 bias C-operands
        Q4 af[4]; float4v bc4[4];
        #pragma unroll
        for (int f = 0; f < 4; ++f) {
            af[f].q = w1f[((e*4 + f)*4 + qq)*16 + mm];
            float4 bb = b1pf[(e*4 + f)*4 + qq];
            bc4[f] = (float4v){bb.x, bb.y, bb.z, bb.w};
        }

        #pragma unroll
        for (int grp = 0; grp < 12; ++grp) {
            // border mask as f16x2 {0,0} or {1,1} from the bitfield
            H2 mv;
            if (!interior) mv.u = ((mskbits >> grp) & 1u) ? 0x3C003C00u : 0u;
            // conv1 (+bias in C): lane (qq,mm) -> channels {qq*8+j, 32+qq*8+j} of pixel mm
            Q4 a0, a1;
            #pragma unroll
            for (int f = 0; f < 4; ++f) {
                float4v d = __builtin_amdgcn_mfma_f32_16x16x32_bf16(
                    af[f].s, bfr[grp].s, bc4[f], 0, 0, 0);
                H2 h01, h23;
                h01.u = pkf16(d[0], d[1]);
                h23.u = pkf16(d[2], d[3]);
                h01.h = pkmax0(h01.h);
                h23.h = pkmax0(h23.h);
                if (!interior) { h01.h = h01.h * mv.h; h23.h = h23.h * mv.h; }
                if      (f == 0) { a0.q.x = h01.u; a0.q.y = h23.u; }
                else if (f == 1) { a0.q.z = h01.u; a0.q.w = h23.u; }
                else if (f == 2) { a1.q.x = h01.u; a1.q.y = h23.u; }
                else             { a1.q.z = h01.u; a1.q.w = h23.u; }
            }
            // conv2 stage 1, direct from registers: T[tap][pixel]
            float4v d2 = __builtin_amdgcn_mfma_f32_16x16x32_f16(
                a0.h, bw0.h, (float4v){0.f,0.f,0.f,0.f}, 0, 0, 0);
            d2 = __builtin_amdgcn_mfma_f32_16x16x32_f16(a1.h, bw1.h, d2, 0, 0, 0);
            if (mm < 9)            // tap = mm; rows = wave-local pixels grp*16+qq*4+r
                *(float4*)&s_T[wv][mm][grp*16 + qq*4] = make_float4(d2[0], d2[1], d2[2], d2[3]);
        }
        // same-wave in-order DS: no explicit drain needed before stage-2 reads.

        // stage 2: thread (qq,mm) -> output rows oy=qq and oy=qq+4
        float o0 = 0.f, o1 = 0.f;
        #pragma unroll
        for (int kh = 0; kh < 3; ++kh) {
            #pragma unroll
            for (int kw = 0; kw < 3; ++kw) {
                o0 += s_T[wv][kh*3 + kw][(qq + kh)*18 + mm + kw];
                o1 += s_T[wv][kh*3 + kw][(qq + 4 + kh)*18 + mm + kw];
            }
        }
        // next expert's s_T writes are same-wave after these reads: HW-ordered.
        acc0 += gval * (o0 + eb2[e]);
        acc1 += gval * (o1 + eb2[e]);
    }
    // wave wv, lane (qq,mm) -> rows ty0+8*wv+qq and +qq+4, col tx0+mm
    size_t o = (size_t)b*65536 + (size_t)(ty0 + wv*8 + qq)*256 + tx0 + mm;
    out[o]        = acc0;
    out[o + 1024] = acc1;    // +4 rows
}

extern "C" void kernel_launch(void* const* d_in, const int* in_sizes, int n_in,
                              void* d_out, int out_size, void* d_ws, size_t ws_size,
                              hipStream_t stream) {
    (void)in_sizes; (void)n_in; (void)out_size; (void)ws_size;
    const float* x     = (const float*)d_in[0];
    const float* ref   = (const float*)d_in[1];
    const float* noise = (const float*)d_in[2];
    const float* mw1   = (const float*)d_in[3];
    const float* mb1   = (const float*)d_in[4];
    const float* mw2   = (const float*)d_in[5];
    const float* mb2   = (const float*)d_in[6];
    const float* enw   = (const float*)d_in[7];
    const float* enb   = (const float*)d_in[8];
    const float* fp    = (const float*)d_in[9];
    const float* wg    = (const float*)d_in[10];
    const float* wn    = (const float*)d_in[11];
    const float* ew1   = (const float*)d_in[12];
    const float* eb1   = (const float*)d_in[13];
    const float* ew2   = (const float*)d_in[14];
    const float* eb2   = (const float*)d_in[15];
    float* out = (float*)d_out;
    float* ws  = (float*)d_ws;

    k_aux    <<<385, 256, 0, stream>>>(ref, x, wg, wn, ew1, ew2, eb1, ws);
    k_gating <<<1, 128, 0, stream>>>(noise, mw1, mb1, mw2, mb2, enw, enb, fp, ws, out);
    k_experts<<<2048, 256, 0, stream>>>(x, eb2, ws, out);
}

// Round 11
// 167.127 us; speedup vs baseline: 1.0373x; 1.0110x over previous
//
#include <hip/hip_runtime.h>
#include <hip/hip_bf16.h>
#include <math.h>

// ---------------- workspace layout (float indices) ----------------
// [0,192)     : refsum partials  [bc=48][chunk=4]
// [192,256)   : gates[b*4+e]
// [256,24832) : gate-dot partials [c=3][chunk=64][b=16][8]  (G[4] then N[4]) - deterministic
// [24832,25088): packed conv1 bias f32x4 (64 float4)  [channel-permuted, C-operand form]
// [25088,29184): packed conv1 A-frags  (1024 uint4)  [channel-permuted, see chan()]
// [29184,31232): packed conv2 B-frags  (512 uint4)
#define WS_GATE 192
#define WS_GNP  256
#define WS_B1P  24832
#define WS_W1F  25088
#define WS_W2F  29184

typedef float    float4v __attribute__((ext_vector_type(4)));
typedef short    short8v __attribute__((ext_vector_type(8)));
typedef _Float16 half8v  __attribute__((ext_vector_type(8)));
typedef _Float16 half2v  __attribute__((ext_vector_type(2)));

union Q4 { uint4 q; short8v s; half8v h; };
union H2 { unsigned u; half2v h; };

__device__ __forceinline__ unsigned short bf16b(float f) {
    unsigned u = __builtin_bit_cast(unsigned, f);
    u = (u + 0x7FFFu + ((u >> 16) & 1u)) >> 16;   // RNE
    return (unsigned short)u;
}

__device__ __forceinline__ unsigned pkbf16(float a, float b) {
#if __has_builtin(__builtin_amdgcn_cvt_pk_bf16_f32)
    return __builtin_bit_cast(unsigned, __builtin_amdgcn_cvt_pk_bf16_f32(a, b));
#else
    return (unsigned)bf16b(a) | ((unsigned)bf16b(b) << 16);
#endif
}

__device__ __forceinline__ unsigned pkf16(float a, float b) {
#if __has_builtin(__builtin_amdgcn_cvt_pkrtz)
    return __builtin_bit_cast(unsigned, __builtin_amdgcn_cvt_pkrtz(a, b));
#else
    union { _Float16 h[2]; unsigned u; } p;
    p.h[0] = (_Float16)a; p.h[1] = (_Float16)b;
    return p.u;
#endif
}

__device__ __forceinline__ half2v pkmax0(half2v a) {
#if __has_builtin(__builtin_elementwise_max)
    return __builtin_elementwise_max(a, (half2v){(_Float16)0, (_Float16)0});
#else
    half2v r;
    r[0] = a[0] > (_Float16)0 ? a[0] : (_Float16)0;
    r[1] = a[1] > (_Float16)0 ? a[1] : (_Float16)0;
    return r;
#endif
}

// ---------------- kernel AUX: refsum (0..191) | gatedots (192..383) | prep (384) ----------------
__global__ void k_aux(const float* __restrict__ ref, const float* __restrict__ x,
                      const float* __restrict__ wg,  const float* __restrict__ wn,
                      const float* __restrict__ ew1, const float* __restrict__ ew2,
                      const float* __restrict__ eb1,
                      float* __restrict__ ws) {
    __shared__ float sh[4][16][8];
    int blk = blockIdx.x, t = threadIdx.x;

    if (blk < 192) {
        // ---- refsum partials: bc = blk>>2, chunk = blk&3 ----
        int bc = blk >> 2, chunk = blk & 3;
        const float4* p4 = (const float4*)(ref + (size_t)bc*65536 + (size_t)chunk*16384);
        float acc = 0.f;
        #pragma unroll
        for (int i = 0; i < 16; ++i) { float4 v = p4[i*256 + t]; acc += v.x + v.y + v.z + v.w; }
        #pragma unroll
        for (int m = 1; m <= 32; m <<= 1) acc += __shfl_xor(acc, m);
        if ((t & 63) == 0) sh[0][0][t >> 6] = acc;
        __syncthreads();
        if (t == 0) ws[bc*4 + chunk] = sh[0][0][0] + sh[0][0][1] + sh[0][0][2] + sh[0][0][3];
        return;
    }
    if (blk < 384) {
        // ---- gate-dot partials: wg/wn read exactly once; DETERMINISTIC per-chunk slots ----
        int r = blk - 192;
        int c = r >> 6, chunk = r & 63;
        int lane = t & 63, wv = t >> 6;
        int hw0 = chunk*1024 + t*4;
        const float4* wg4 = (const float4*)wg;
        const float4* wn4 = (const float4*)wn;
        const float4* x4  = (const float4*)x;
        float4 G[4], Nw[4];
        #pragma unroll
        for (int i = 0; i < 4; ++i) {
            G[i]  = wg4[c*65536 + hw0 + i];
            Nw[i] = wn4[c*65536 + hw0 + i];
        }
        for (int b = 0; b < 16; ++b) {
            float4 xv = x4[(b*3 + c)*16384 + chunk*256 + t];
            float xs[4] = {xv.x, xv.y, xv.z, xv.w};
            float aG[4] = {0,0,0,0}, aN[4] = {0,0,0,0};
            #pragma unroll
            for (int i = 0; i < 4; ++i) {
                aG[0] += xs[i]*G[i].x;  aG[1] += xs[i]*G[i].y;
                aG[2] += xs[i]*G[i].z;  aG[3] += xs[i]*G[i].w;
                aN[0] += xs[i]*Nw[i].x; aN[1] += xs[i]*Nw[i].y;
                aN[2] += xs[i]*Nw[i].z; aN[3] += xs[i]*Nw[i].w;
            }
            #pragma unroll
            for (int m = 1; m <= 32; m <<= 1) {
                #pragma unroll
                for (int e = 0; e < 4; ++e) {
                    aG[e] += __shfl_xor(aG[e], m);
                    aN[e] += __shfl_xor(aN[e], m);
                }
            }
            if (lane == 0) {
                #pragma unroll
                for (int e = 0; e < 4; ++e) { sh[wv][b][e] = aG[e]; sh[wv][b][4+e] = aN[e]; }
            }
        }
        __syncthreads();
        if (t < 128) {
            int b = t >> 3, s = t & 7;
            float v = sh[0][b][s] + sh[1][b][s] + sh[2][b][s] + sh[3][b][s];
            ws[WS_GNP + ((size_t)(c*64 + chunk)*16 + b)*8 + s] = v;
        }
        return;
    }
    // ---- prep: pack conv weights + bias into MFMA-ready frags ----
    // Channel permutation: conv1 MFMA f, D-row rho produces ORIGINAL channel
    //   chan(f,rho) = (rho>>2)*8 + (f&1)*4 + (rho&3) + (f>>1)*32
    // so that lane (qq,mm) ends holding channels {qq*8..qq*8+7} (f=0,1) and
    // {32+qq*8..+7} (f=2,3) of pixel mm == conv2's A-fragment, in-register.
    uint4* w1f = (uint4*)(ws + WS_W1F);
    for (int i = t; i < 1024; i += 256) {   // i = ((e*4+f)*4+qq)*16+mm ; A-row = mm
        int mm = i & 15, r = i >> 4, qq = r & 3, r2 = r >> 2, f = r2 & 3, e = r2 >> 2;
        int chan = (mm >> 2)*8 + (f & 1)*4 + (mm & 3) + (f >> 1)*32;
        const float* w1 = ew1 + e*1728 + chan*27 + qq*8;
        int navail = 27 - qq*8;             // 8,8,8,3 (k>=27 zero-padded => B-frag garbage OK)
        float v[8];
        #pragma unroll
        for (int j = 0; j < 8; ++j) v[j] = (j < navail) ? w1[j] : 0.f;
        uint4 q;
        q.x = pkbf16(v[0], v[1]); q.y = pkbf16(v[2], v[3]);
        q.z = pkbf16(v[4], v[5]); q.w = pkbf16(v[6], v[7]);
        w1f[i] = q;
    }
    uint4* w2f = (uint4*)(ws + WS_W2F);
    for (int i = t; i < 512; i += 256) {    // i = ((e*16+mm)*2+ks)*4+qq
        int qq = i & 3, r = i >> 2, ks = r & 1, r2 = r >> 1, mm = r2 & 15, e = r2 >> 4;
        uint4 q = make_uint4(0, 0, 0, 0);
        if (mm < 9) {                       // tap = mm, c = ks*32+qq*8+j (original labels)
            float v[8];
            #pragma unroll
            for (int j = 0; j < 8; ++j) v[j] = ew2[e*576 + (ks*32 + qq*8 + j)*9 + mm];
            q.x = pkf16(v[0], v[1]); q.y = pkf16(v[2], v[3]);
            q.z = pkf16(v[4], v[5]); q.w = pkf16(v[6], v[7]);
        }
        w2f[i] = q;
    }
    // packed conv1 bias as f32x4 C-operand: [(e*4+f)*4+qq] holds bias for D-rows qq*4+r
    // = original channels qq*8 + (f&1)*4 + r + (f>>1)*32  (contiguous in r)
    float4* b1pf = (float4*)(ws + WS_B1P);
    if (t < 64) {
        int qq = t & 3, r = t >> 2, f = r & 3, e = r >> 2;
        b1pf[t] = *(const float4*)(eb1 + e*64 + qq*8 + (f & 1)*4 + (f >> 1)*32);
    }
}

// -------- kernel C: reduce partials (fixed order, coalesced) + prompt + top-k + gates + loss ----
__global__ void k_gating(const float* __restrict__ noise,
                         const float* __restrict__ mw1, const float* __restrict__ mb1,
                         const float* __restrict__ mw2, const float* __restrict__ mb2,
                         const float* __restrict__ enw, const float* __restrict__ enb,
                         const float* __restrict__ fp,
                         float* __restrict__ ws, float* __restrict__ out) {
    __shared__ float GN2[48*8];          // [(b*3+c)][4G|4N]
    __shared__ float gL[16][4], pL[16][4], cvs[2];
    int t = threadIdx.x;                 // 128 threads
    {
        // thread t owns (b = t>>3, s = t&7); plane (c,ch) is 128 consecutive floats
        // so each load below is a fully-coalesced 512B wavefront read. Summation
        // order over ch is ascending, identical to the previous serial order.
        int b = t >> 3, s = t & 7;
        #pragma unroll
        for (int c = 0; c < 3; ++c) {
            float v = 0.f;
            #pragma unroll 8
            for (int ch = 0; ch < 64; ++ch)
                v += ws[WS_GNP + (size_t)(c*64 + ch)*128 + t];
            GN2[(b*3 + c)*8 + s] = v;
        }
    }
    __syncthreads();
    if (t < 16) {
        int b = t;
        float sc[3];
        for (int c = 0; c < 3; ++c) {
            int bc = b*3 + c;
            sc[c] = (ws[bc*4] + ws[bc*4+1] + ws[bc*4+2] + ws[bc*4+3]) * (1.f/256.f);
        }
        float pooled[12];
        for (int i = 0; i < 12; ++i) { int r = i % 6; pooled[i] = (r < 3) ? sc[r] : 0.f; }
        float m1[6];
        for (int o = 0; o < 6; ++o) {
            float a = mb1[o];
            for (int i = 0; i < 12; ++i) a += mw1[o*12 + i] * pooled[i];
            m1[o] = fmaxf(a, 0.f);
        }
        float m2[6];
        for (int o = 0; o < 6; ++o) {
            float a = mb2[o];
            for (int i = 0; i < 6; ++i) a += mw2[o*6 + i] * m1[i];
            m2[o] = a * fp[(size_t)o * 33024];   // * fre_prompt[o,0,0]
        }
        float dc[3];
        for (int o = 0; o < 3; ++o) {            // only real-part channels matter
            float a = enb[o];
            for (int i = 0; i < 6; ++i) a += enw[o*6 + i] * m2[i];
            dc[o] = fmaxf(a, 0.f) * (1.f/256.f); // mean of irfft2 = Re(DC)/256
        }
        float mx = fmaxf(dc[0], fmaxf(dc[1], dc[2]));
        float e0 = expf(dc[0]-mx), e1 = expf(dc[1]-mx), e2 = expf(dc[2]-mx);
        float inv = 1.f / (e0 + e1 + e2);
        float pc[3] = { e0*inv + 1.f, e1*inv + 1.f, e2*inv + 1.f };
        float cl[4], sg[4], nz[4];
        for (int e = 0; e < 4; ++e) {
            float a = 0.f, nr = 0.f;
            for (int c = 0; c < 3; ++c) {
                a  += pc[c] * GN2[(b*3 + c)*8 + e];
                nr += pc[c] * GN2[(b*3 + c)*8 + 4 + e];
            }
            cl[e] = a;
            float sp = (nr > 20.f) ? nr : log1pf(expf(nr));
            sg[e] = sp + 0.01f;
            nz[e] = a + noise[b*4 + e] * sg[e];
        }
        int i0 = 0; float v0 = nz[0];
        for (int e = 1; e < 4; ++e) if (nz[e] > v0) { v0 = nz[e]; i0 = e; }
        int i1 = -1; float v1 = -3.4e38f;
        for (int e = 0; e < 4; ++e) if (e != i0 && nz[e] > v1) { v1 = nz[e]; i1 = e; }
        float v2 = -3.4e38f;
        for (int e = 0; e < 4; ++e) if (e != i0 && e != i1 && nz[e] > v2) v2 = nz[e];
        float ex = expf(v1 - v0), den = 1.f + ex;
        float gate[4] = {0.f, 0.f, 0.f, 0.f};
        gate[i0] = 1.f/den; gate[i1] = ex/den;
        for (int e = 0; e < 4; ++e) {
            ws[WS_GATE + b*4 + e] = gate[e];
            gL[b][e] = gate[e];
            float thr = (nz[e] > v2) ? v2 : v1;   // thr_in = 3rd-largest, thr_out = 2nd
            pL[b][e] = 0.5f * (1.f + erff((cl[e] - thr) / sg[e] * 0.70710678118f));
        }
    }
    __syncthreads();
    if (t < 2) {
        float v[4];
        for (int e = 0; e < 4; ++e) {
            float s = 0.f;
            for (int b = 0; b < 16; ++b) s += (t == 0) ? gL[b][e] : pL[b][e];
            v[e] = s;
        }
        float mean = 0.25f * (v[0] + v[1] + v[2] + v[3]);
        float var = 0.f;
        for (int e = 0; e < 4; ++e) { float d = v[e] - mean; var += d*d; }
        var *= (1.f/3.f);
        cvs[t] = var / (mean*mean + 1e-10f);
    }
    __syncthreads();
    if (t == 0) out[1048576] = (cvs[0] + cvs[1]) * 0.01f;
}

// -------- kernel D: fused expert convs, zero-exchange, 16x32 TALL TILES --------
// 2048 blocks; tile = 16 wide x 32 high; wave wv owns output rows 8*wv..8*wv+7.
// Halo amortization: 12 grps / 128 outputs = 1.125 MFMA-groups per output
// (was 7/64 = 1.31) => -14% MFMA + conversions + gather. Math verified in R10.
// __launch_bounds__(256,3): VGPR cap ~170 — real demand ~150 (bfr[12]=48 held
// + af/bw/acc/gather temps). At (256,4) cap 128 this SPILLED (R10: WRITE 39MB).
// 3 blocks/CU = 12 waves/CU; LDS 28.2KB*3 = 84.6KB fits.
// Spill tripwire: WRITE_SIZE must stay ~4.1 MB, else revert to R9 16x16.
__global__ __launch_bounds__(256, 3)
void k_experts(const float* __restrict__ x, const float* __restrict__ eb2,
               const float* __restrict__ ws, float* __restrict__ out) {
    __shared__ __align__(16) char s_raw[28224];  // union: in_s f32[3][36][24] | s_T f32[4][9][196]
    float* in_s = (float*)s_raw;
    typedef float sT_t[9][196];
    sT_t* s_T = (sT_t*)s_raw;

    int t = threadIdx.x;
    int bid = blockIdx.x;
    int logical = (bid & 7) * 256 + (bid >> 3);   // XCD-affinity stripe over 2048
    int b = logical >> 7, tile = logical & 127;   // 8 tile-rows x 16 tile-cols
    int ty0 = (tile >> 4) * 32, tx0 = (tile & 15) * 16;
    const float* xb = x + (size_t)b * 196608;

    // window rows [ty0-2, ty0+33], cols [tx0-4, tx0+19]
    bool interior = (ty0 > 0) && (ty0 < 224) && (tx0 > 0) && (tx0 < 240);

    // ---- load input tile f32 [3][36][24], window origin (ty0-2, tx0-4) ----
    if (interior) {
        // 648 float4s, 16B-aligned, all in-bounds.
        float4* in_s4 = (float4*)in_s;
        int base4 = ((ty0 - 2)*256 + tx0 - 4) >> 2;
        const float4* xb4 = (const float4*)xb;
        #pragma unroll
        for (int it = 0; it < 3; ++it) {
            int idx = t + it*256;
            if (idx < 648) {
                int ci = idx / 216, rem = idx - ci*216;
                int iy = rem / 6,   ix4 = rem - iy*6;
                in_s4[idx] = xb4[ci*16384 + iy*64 + ix4 + base4];
            }
        }
    } else {
        for (int i = t; i < 2592; i += 256) {
            int ci = i / 864, r = i - ci*864, iy = r / 24, ix = r - iy*24;
            int gy = ty0 - 2 + iy, gx = tx0 - 4 + ix;
            float v = 0.f;
            if ((unsigned)gy < 256u && (unsigned)gx < 256u) v = xb[ci*65536 + gy*256 + gx];
            in_s[i] = v;
        }
    }
    __syncthreads();

    int lane = t & 63, wv = t >> 6;
    int qq = lane >> 4, mm = lane & 15;

    // per-lane k->tile-offset map (k = qq*8+j), [3][36][24] layout; k>=27 -> addr 0 (weights 0)
    int offj[8];
    #pragma unroll
    for (int j = 0; j < 8; ++j) {
        int k = qq*8 + j;
        if (k < 27) { int ci = k/9, r = k - ci*9, kh = r/3, kw = r - kh*3;
                      offj[j] = ci*864 + kh*24 + kw; }
        else offj[j] = 0;
    }

    // ---- build conv1 B-frags: wave wv hidden field = 10 rows x 18 cols (180 px, 12 grps) ----
    // hidden local p: py = p/18 (0..9), px = p%18; window input row = 8*wv + py.
    Q4 bfr[12];
    unsigned mskbits = 0;
    #pragma unroll
    for (int grp = 0; grp < 12; ++grp) {
        int p = grp*16 + mm;
        int py = p/18, px = p - py*18;
        int base = (p < 180) ? ((8*wv + py)*24 + px + 2) : 0;
        float v[8];
        #pragma unroll
        for (int j = 0; j < 8; ++j)
            v[j] = in_s[base + offj[j]];            // no mask: garbage * 0-weight = 0
        bfr[grp].q.x = pkbf16(v[0], v[1]); bfr[grp].q.y = pkbf16(v[2], v[3]);
        bfr[grp].q.z = pkbf16(v[4], v[5]); bfr[grp].q.w = pkbf16(v[6], v[7]);
        int gy = ty0 + 8*wv + py - 1, gx = tx0 - 1 + px;
        if (((unsigned)gy < 256u) && ((unsigned)gx < 256u)) mskbits |= (1u << grp);
    }
    __syncthreads();   // all waves done with in_s before any s_T write (aliased)

    const float4 gates = *(const float4*)(ws + WS_GATE + b*4);
    float gv[4] = {gates.x, gates.y, gates.z, gates.w};
    const uint4*  w1f  = (const uint4*)(ws + WS_W1F);
    const uint4*  w2f  = (const uint4*)(ws + WS_W2F);
    const float4* b1pf = (const float4*)(ws + WS_B1P);
    float acc0 = 0.f, acc1 = 0.f;

    for (int e = 0; e < 4; ++e) {
        float gval = gv[e];
        if (gval == 0.f) continue;                 // block-uniform (exactly 2 active)

        // pre-packed conv2 B-frags
        Q4 bw0, bw1;
        bw0.q = w2f[((e*16 + mm)*2 + 0)*4 + qq];
        bw1.q = w2f[((e*16 + mm)*2 + 1)*4 + qq];
        // pre-packed (channel-permuted) conv1 A-frags + f32 bias C-operands
        Q4 af[4]; float4v bc4[4];
        #pragma unroll
        for (int f = 0; f < 4; ++f) {
            af[f].q = w1f[((e*4 + f)*4 + qq)*16 + mm];
            float4 bb = b1pf[(e*4 + f)*4 + qq];
            bc4[f] = (float4v){bb.x, bb.y, bb.z, bb.w};
        }

        #pragma unroll
        for (int grp = 0; grp < 12; ++grp) {
            // border mask as f16x2 {0,0} or {1,1} from the bitfield
            H2 mv;
            if (!interior) mv.u = ((mskbits >> grp) & 1u) ? 0x3C003C00u : 0u;
            // conv1 (+bias in C): lane (qq,mm) -> channels {qq*8+j, 32+qq*8+j} of pixel mm
            Q4 a0, a1;
            #pragma unroll
            for (int f = 0; f < 4; ++f) {
                float4v d = __builtin_amdgcn_mfma_f32_16x16x32_bf16(
                    af[f].s, bfr[grp].s, bc4[f], 0, 0, 0);
                H2 h01, h23;
                h01.u = pkf16(d[0], d[1]);
                h23.u = pkf16(d[2], d[3]);
                h01.h = pkmax0(h01.h);
                h23.h = pkmax0(h23.h);
                if (!interior) { h01.h = h01.h * mv.h; h23.h = h23.h * mv.h; }
                if      (f == 0) { a0.q.x = h01.u; a0.q.y = h23.u; }
                else if (f == 1) { a0.q.z = h01.u; a0.q.w = h23.u; }
                else if (f == 2) { a1.q.x = h01.u; a1.q.y = h23.u; }
                else             { a1.q.z = h01.u; a1.q.w = h23.u; }
            }
            // conv2 stage 1, direct from registers: T[tap][pixel]
            float4v d2 = __builtin_amdgcn_mfma_f32_16x16x32_f16(
                a0.h, bw0.h, (float4v){0.f,0.f,0.f,0.f}, 0, 0, 0);
            d2 = __builtin_amdgcn_mfma_f32_16x16x32_f16(a1.h, bw1.h, d2, 0, 0, 0);
            if (mm < 9)            // tap = mm; rows = wave-local pixels grp*16+qq*4+r
                *(float4*)&s_T[wv][mm][grp*16 + qq*4] = make_float4(d2[0], d2[1], d2[2], d2[3]);
        }
        // same-wave in-order DS: no explicit drain needed before stage-2 reads.

        // stage 2: thread (qq,mm) -> output rows oy=qq and oy=qq+4
        float o0 = 0.f, o1 = 0.f;
        #pragma unroll
        for (int kh = 0; kh < 3; ++kh) {
            #pragma unroll
            for (int kw = 0; kw < 3; ++kw) {
                o0 += s_T[wv][kh*3 + kw][(qq + kh)*18 + mm + kw];
                o1 += s_T[wv][kh*3 + kw][(qq + 4 + kh)*18 + mm + kw];
            }
        }
        // next expert's s_T writes are same-wave after these reads: HW-ordered.
        acc0 += gval * (o0 + eb2[e]);
        acc1 += gval * (o1 + eb2[e]);
    }
    // wave wv, lane (qq,mm) -> rows ty0+8*wv+qq and +qq+4, col tx0+mm
    size_t o = (size_t)b*65536 + (size_t)(ty0 + wv*8 + qq)*256 + tx0 + mm;
    out[o]        = acc0;
    out[o + 1024] = acc1;    // +4 rows
}

extern "C" void kernel_launch(void* const* d_in, const int* in_sizes, int n_in,
                              void* d_out, int out_size, void* d_ws, size_t ws_size,
                              hipStream_t stream) {
    (void)in_sizes; (void)n_in; (void)out_size; (void)ws_size;
    const float* x     = (const float*)d_in[0];
    const float* ref   = (const float*)d_in[1];
    const float* noise = (const float*)d_in[2];
    const float* mw1   = (const float*)d_in[3];
    const float* mb1   = (const float*)d_in[4];
    const float* mw2   = (const float*)d_in[5];
    const float* mb2   = (const float*)d_in[6];
    const float* enw   = (const float*)d_in[7];
    const float* enb   = (const float*)d_in[8];
    const float* fp    = (const float*)d_in[9];
    const float* wg    = (const float*)d_in[10];
    const float* wn    = (const float*)d_in[11];
    const float* ew1   = (const float*)d_in[12];
    const float* eb1   = (const float*)d_in[13];
    const float* ew2   = (const float*)d_in[14];
    const float* eb2   = (const float*)d_in[15];
    float* out = (float*)d_out;
    float* ws  = (float*)d_ws;

    k_aux    <<<385, 256, 0, stream>>>(ref, x, wg, wn, ew1, ew2, eb1, ws);
    k_gating <<<1, 128, 0, stream>>>(noise, mw1, mb1, mw2, mb2, enw, enb, fp, ws, out);
    k_experts<<<2048, 256, 0, stream>>>(x, eb2, ws, out);
}